// Round 7
// baseline (699.965 us; speedup 1.0000x reference)
//
#include <hip/hip_runtime.h>
#include <hip/hip_bf16.h>
#include <stdint.h>

typedef __attribute__((ext_vector_type(8))) short bf16x8;
typedef __attribute__((ext_vector_type(4))) float f32x4;
typedef __attribute__((ext_vector_type(4))) unsigned short ushort4_t;

__device__ __forceinline__ unsigned short f2bf(float f) {
  union { float f; unsigned int i; } x; x.f = f;
  return (unsigned short)((x.i + 0x7fffu + ((x.i >> 16) & 1u)) >> 16);
}

// async global->LDS, 16B per lane; LDS dest is wave-uniform base + lane*16
__device__ __forceinline__ void gl_lds16(const void* g, void* l) {
  __builtin_amdgcn_global_load_lds(
      (const __attribute__((address_space(1))) unsigned int*)(uintptr_t)g,
      (__attribute__((address_space(3))) unsigned int*)(uint32_t)(uintptr_t)l,
      16, 0, 0);
}

// raw barrier (no vmcnt/lgkmcnt drain!) with compiler memory fences
__device__ __forceinline__ void bar() {
  asm volatile("" ::: "memory");
  __builtin_amdgcn_s_barrier();
  asm volatile("" ::: "memory");
}

// inv_freq[j] = 10000^(-j/16), j = 0..15 (d_half=32, 16 freqs)
__constant__ float INVF[16] = {
  1.0f,   0.56234132519f,  0.31622776601f,  0.17782794100f,
  0.1f,   0.056234132519f, 0.031622776601f, 0.017782794100f,
  0.01f,  0.0056234132519f,0.0031622776601f,0.0017782794100f,
  0.001f, 0.00056234132519f,0.00031622776601f,0.00017782794100f
};

// ---- fp32 -> bf16 bulk convert (x) ----
__global__ __launch_bounds__(256) void k_conv_x(const float4* __restrict__ src,
                                                ushort4_t* __restrict__ dst, int n4) {
  int i = blockIdx.x * 256 + threadIdx.x;
  if (i < n4) {
    float4 v = src[i];
    ushort4_t r = { f2bf(v.x), f2bf(v.y), f2bf(v.z), f2bf(v.w) };
    dst[i] = r;
  }
}

// ---- fp32 RxC -> bf16 CxR transpose (weights to B^T layout) ----
__global__ __launch_bounds__(256) void k_transpose_bf16(const float* __restrict__ src,
                                                        unsigned short* __restrict__ dst,
                                                        int R, int C) {
  __shared__ unsigned short tile[64][65];
  const int bj = blockIdx.x, bi = blockIdx.y;
  const int t = threadIdx.x, lr = t >> 6, lc = t & 63;
  #pragma unroll
  for (int i = 0; i < 16; i++) {
    int r = i * 4 + lr;
    tile[r][lc] = f2bf(src[(size_t)(bi * 64 + r) * C + bj * 64 + lc]);
  }
  __syncthreads();
  #pragma unroll
  for (int i = 0; i < 16; i++) {
    int r = i * 4 + lr;
    dst[(size_t)(bj * 64 + r) * R + bi * 64 + lc] = tile[lc][r];
  }
}

// ---- Per-wave software-pipelined GEMM: C[M,N] = A[M,K]*B[N,K]^T ----
// (unchanged from R6 -- best GEMM so far, 214 us / 950 TF. Attn is this
// round's experiment.)

#define LDA(dst, base, hm)                                                      \
  do {                                                                          \
    _Pragma("unroll") for (int t_ = 0; t_ < 4; t_++) {                          \
      dst[0][t_] = *(const bf16x8*)&base[(wm * 128 + (hm) * 64 + t_ * 16 + cl) * 64 + cf0]; \
      dst[1][t_] = *(const bf16x8*)&base[(wm * 128 + (hm) * 64 + t_ * 16 + cl) * 64 + cf1]; \
    }                                                                           \
  } while (0)

#define LDB(dst, base, hn)                                                      \
  do {                                                                          \
    _Pragma("unroll") for (int u_ = 0; u_ < 2; u_++) {                          \
      dst[0][u_] = *(const bf16x8*)&base[(wn * 64 + (hn) * 32 + u_ * 16 + cl) * 64 + cf0]; \
      dst[1][u_] = *(const bf16x8*)&base[(wn * 64 + (hn) * 32 + u_ * 16 + cl) * 64 + cf1]; \
    }                                                                           \
  } while (0)

#define MFMA_Q(hm, hn, AFR, BVR)                                                \
  do {                                                                          \
    __builtin_amdgcn_s_setprio(1);                                              \
    _Pragma("unroll") for (int kc_ = 0; kc_ < 2; kc_++)                         \
      _Pragma("unroll") for (int mt_ = 0; mt_ < 4; mt_++)                       \
        _Pragma("unroll") for (int u_ = 0; u_ < 2; u_++)                        \
          acc[(hm) * 4 + mt_][(hn) * 2 + u_] =                                  \
              __builtin_amdgcn_mfma_f32_16x16x32_bf16(                          \
                  AFR[kc_][mt_], BVR[kc_][u_],                                  \
                  acc[(hm) * 4 + mt_][(hn) * 2 + u_], 0, 0, 0);                 \
    __builtin_amdgcn_s_setprio(0);                                              \
  } while (0)

#define STAGE_A(tile_, half_)                                                   \
  do {                                                                          \
    const int so_ = ((tile_) & 1) * 16384;                                      \
    const int ko_ = (tile_) * 64;                                               \
    gl_lds16(aP[(half_) * 2] + ko_,     &As[so_ + ((half_) * 2) * 4096 + ldsW]);     \
    gl_lds16(aP[(half_) * 2 + 1] + ko_, &As[so_ + ((half_) * 2 + 1) * 4096 + ldsW]); \
  } while (0)

#define STAGE_B(tile_, half_)                                                   \
  do {                                                                          \
    const int so_ = ((tile_) & 1) * 16384;                                      \
    const int ko_ = (tile_) * 64;                                               \
    gl_lds16(bP[(half_) * 2] + ko_,     &Bs[so_ + ((half_) * 2) * 4096 + ldsW]);     \
    gl_lds16(bP[(half_) * 2 + 1] + ko_, &Bs[so_ + ((half_) * 2 + 1) * 4096 + ldsW]); \
  } while (0)

#define SBAR() __builtin_amdgcn_sched_barrier(0)

template<int F32OUT, int ROPE>
__global__ __launch_bounds__(512, 2) void k_gemm_bt(
    const unsigned short* __restrict__ A, const unsigned short* __restrict__ B,
    unsigned short* __restrict__ Cb, float* __restrict__ Cf,
    const float* __restrict__ bias, int M, int N, int K) {
  __shared__ __align__(16) unsigned short As[2 * 256 * 64];  // 64 KB
  __shared__ __align__(16) unsigned short Bs[2 * 256 * 64];  // 64 KB
  const int tid = threadIdx.x;
  const int lane = tid & 63, wid = tid >> 6;
  const int cl = lane & 15, gr = lane >> 4;
  const int wm = wid >> 2, wn = wid & 3;     // 2M x 4N wave grid
  const int l8 = lane >> 3, l7 = lane & 7;

  // XCD-aware bijective block swizzle (requires nwg % 8 == 0; holds here)
  const int gx = gridDim.x;
  const int nwg = gx * gridDim.y;
  const int fb = blockIdx.y * gx + blockIdx.x;
  const int q = nwg >> 3;
  const int nid = (fb & 7) * q + (fb >> 3);
  const int bx = nid % gx, by = nid / gx;
  const int mBase = by * 256, nBase = bx * 256;

  const int KT = K >> 6;                 // 64-wide K chunks (16 here)
  const int ldsW = (wid * 8) * 64;       // wave-uniform LDS row-base offset
  const int cf0 = ((0 * 4 + gr) ^ (cl & 7)) * 8;
  const int cf1 = ((1 * 4 + gr) ^ (cl & 7)) * 8;

  // per-thread global source pointers (include row and pre-swizzled chunk)
  const unsigned short* aP[4];
  const unsigned short* bP[4];
  #pragma unroll
  for (int i = 0; i < 4; i++) {
    aP[i] = A + (size_t)(mBase + i * 64 + wid * 8 + l8) * K + (l7 ^ l8) * 8;
    bP[i] = B + (size_t)(nBase + i * 64 + wid * 8 + l8) * K + (l7 ^ l8) * 8;
  }

  const f32x4 zero4 = {0.f, 0.f, 0.f, 0.f};
  f32x4 acc[8][4];
  #pragma unroll
  for (int a = 0; a < 8; a++)
    #pragma unroll
    for (int b = 0; b < 4; b++) acc[a][b] = zero4;

  // prologue: stage tile 0 into slot 0, wait, publish
  STAGE_A(0, 0); STAGE_A(0, 1); STAGE_B(0, 0); STAGE_B(0, 1);
  asm volatile("s_waitcnt vmcnt(0)" ::: "memory");
  bar();

  bf16x8 af0[2][4], af1[2][4], bva[2][2], bvb[2][2];

  for (int c = 0; c < KT; ++c) {
    const int s = c & 1;
    const unsigned short* as_ = As + s * 16384;
    const unsigned short* bs_ = Bs + s * 16384;

    // stage tile c+1 into the other slot (async, vm-counted)
    if (c + 1 < KT) {
      STAGE_A(c + 1, 0); STAGE_A(c + 1, 1);
      STAGE_B(c + 1, 0); STAGE_B(c + 1, 1);
    }

    // ds-issue in counted order: [af0:8][bva:4] [bvb:4] [af1:8]
    LDA(af0, as_, 0);
    LDB(bva, bs_, 0);
    SBAR();
    LDB(bvb, bs_, 1);
    SBAR();
    LDA(af1, as_, 1);
    SBAR();

    asm volatile("s_waitcnt lgkmcnt(12)" ::: "memory");  // af0+bva landed
    SBAR();
    MFMA_Q(0, 0, af0, bva);
    asm volatile("s_waitcnt lgkmcnt(8)" ::: "memory");   // bvb landed
    SBAR();
    MFMA_Q(0, 1, af0, bvb);
    asm volatile("s_waitcnt lgkmcnt(0)" ::: "memory");   // af1 landed
    SBAR();
    MFMA_Q(1, 1, af1, bvb);
    MFMA_Q(1, 0, af1, bva);

    // tile end: publish staged tile c+1 (issued a full tile earlier)
    if (c + 1 < KT) {
      asm volatile("s_waitcnt vmcnt(0)" ::: "memory");
      bar();
    }
  }

  if (ROPE && nBase < 2048) {  // q or k region of qkv output (wave-uniform)
    const float f2 = INVF[cl];
    #pragma unroll
    for (int amt = 0; amt < 8; amt++)
      #pragma unroll
      for (int r = 0; r < 4; r++) {
        const int sp = (mBase + wm * 128 + amt * 16 + gr * 4 + r) & 255;
        float sh, ch, sw, cw;
        __sincosf((float)(sp >> 4) * f2, &sh, &ch);
        __sincosf((float)(sp & 15) * f2, &sw, &cw);
        const float a = acc[amt][0][r], b = acc[amt][1][r];
        const float cc = acc[amt][2][r], d = acc[amt][3][r];
        acc[amt][0][r] = a * ch - b * sh;
        acc[amt][1][r] = b * ch + a * sh;
        acc[amt][2][r] = cc * cw - d * sw;
        acc[amt][3][r] = d * cw + cc * sw;
      }
  }

  // C/D layout (m89-verified): col = lane&15, row = (lane>>4)*4 + reg
  #pragma unroll
  for (int amt = 0; amt < 8; amt++)
    #pragma unroll
    for (int nt = 0; nt < 4; nt++)
      #pragma unroll
      for (int r = 0; r < 4; r++) {
        const int row = mBase + wm * 128 + amt * 16 + gr * 4 + r;
        const int col = nBase + wn * 64 + nt * 16 + cl;
        const float v = acc[amt][nt][r];
        if (F32OUT) Cf[(size_t)row * N + col] = v + bias[col];
        else        Cb[(size_t)row * N + col] = f2bf(v);
      }
}

// ---- flash attention (RoPE pre-applied): one block per (n, head); 4 waves x 64 q
//
// R7 experiment (counters: 229us, MfmaUtil ~1-7%, HBM 16% -> latency/LDS/sync
// bound, not compute/BW):
//  1. kf[kc][nt] hoisted out of the mt loop: QK-phase K reads drop 32->8
//     b128/wave/tc (was re-read 4x). Same MFMA order -> bitwise identical.
//  2. __syncthreads (vmcnt(0)+lgkmcnt(0) drain) replaced by raw bar() +
//     per-wave counted waits. K-stage gl_lds issued BEFORE the 8 V-prefetch
//     globals, so vmcnt(8) at the tc-end barrier retires the K-stage while V
//     loads stay in flight across the barrier (consumed at next Vt-write,
//     compiler inserts the wait). Hazard audit: Vt is the only cross-wave LDS
//     data (P lives in wave-private Qp[wid]); BAR1 (after QK/P, preceded by
//     own lgkmcnt(0)) guards Vt-write visibility + all Kt reads done before
//     restage; BAR2 (tc<3, preceded by vmcnt(8)+lgkmcnt(0)) guards staged-K
//     visibility + PV's Vt reads done before next overwrite.
//  3. setprio(1) around QK and PV MFMA clusters (m191: +4-7% on attn).
__global__ __launch_bounds__(256, 3) void k_attn(const unsigned short* __restrict__ qkv,
                                                 unsigned short* __restrict__ attn_out) {
  __shared__ __align__(16) unsigned short Qp[4][64 * 64];  // per-wave Q, then P
  __shared__ __align__(16) unsigned short Kt[64 * 64];
  __shared__ __align__(16) unsigned short Vt[64 * 64];     // V^T, pi-permuted cols
  const int blk = blockIdx.x;
  const int n = blk >> 4, h = blk & 15;
  const int tid = threadIdx.x;
  const int lane = tid & 63, wid = tid >> 6;
  const int cl = lane & 15, gr = lane >> 4;
  const int l8 = lane >> 3, l7 = lane & 7;
  const unsigned short* qbase = qkv + (size_t)n * 256 * 3072 + h * 64;
  const unsigned short* kbase = qbase + 1024;
  const unsigned short* vbase = qbase + 2048;

  #pragma unroll
  for (int i = 0; i < 8; i++)
    gl_lds16(qbase + (size_t)(wid * 64 + i * 8 + l8) * 3072 + (l7 ^ l8) * 8,
             &Qp[wid][i * 8 * 64]);
  #pragma unroll
  for (int i = 0; i < 2; i++) {
    const int r0 = (wid * 2 + i) * 8;
    gl_lds16(kbase + (size_t)(r0 + l8) * 3072 + (l7 ^ l8) * 8, &Kt[r0 * 64]);
  }

  unsigned int vr[2][4];
  #pragma unroll
  for (int i = 0; i < 2; i++) {
    const int u = i * 256 + tid;
    const int t0 = u >> 5, d = (u & 31) * 2;
    #pragma unroll
    for (int k = 0; k < 4; k++)
      vr[i][k] = *(const unsigned int*)(vbase + (size_t)(t0 + 16 * k) * 3072 + d);
  }
  __syncthreads();   // prologue: Q/K staged + V regs en route (full drain ok once)

  bf16x8 qf[4][2];
  #pragma unroll
  for (int mt = 0; mt < 4; mt++)
    #pragma unroll
    for (int kc = 0; kc < 2; kc++)
      qf[mt][kc] = *(const bf16x8*)&Qp[wid][(mt * 16 + cl) * 64 + ((kc * 4 + gr) ^ (cl & 7)) * 8];

  const f32x4 zero4 = {0.f, 0.f, 0.f, 0.f};
  f32x4 o[4][4];
  float lsum[4][4];
  #pragma unroll
  for (int a = 0; a < 4; a++)
    #pragma unroll
    for (int b = 0; b < 4; b++) { o[a][b] = zero4; lsum[a][b] = 0.f; }

  for (int tc = 0; tc < 4; tc++) {
    // write V(tc) regs -> Vt, permuted + swizzled
    #pragma unroll
    for (int i = 0; i < 2; i++) {
      const int u = i * 256 + tid;
      const int t0 = u >> 5, d = (u & 31) * 2;
      const unsigned int r0 = vr[i][0], r1 = vr[i][1], r2 = vr[i][2], r3 = vr[i][3];
      uint2 lo, hi;
      lo.x = (r0 & 0xffffu) | (r1 << 16);
      lo.y = (r2 & 0xffffu) | (r3 << 16);
      hi.x = (r0 >> 16) | (r1 & 0xffff0000u);
      hi.y = (r2 >> 16) | (r3 & 0xffff0000u);
      *(uint2*)&Vt[d * 64 + ((t0 >> 1) ^ (d & 7)) * 8 + (t0 & 1) * 4] = lo;
      const int d1 = d + 1;
      *(uint2*)&Vt[d1 * 64 + ((t0 >> 1) ^ (d1 & 7)) * 8 + (t0 & 1) * 4] = hi;
    }

    // hoisted K fragments for this K-tile: 8 b128 (was 32, re-read per mt)
    bf16x8 kf[2][4];
    #pragma unroll
    for (int kc = 0; kc < 2; kc++)
      #pragma unroll
      for (int nt = 0; nt < 4; nt++)
        kf[kc][nt] = *(const bf16x8*)&Kt[(nt * 16 + cl) * 64 + ((kc * 4 + gr) ^ (cl & 7)) * 8];

    // QK + exp + P write, one mt at a time
    #pragma unroll
    for (int mt = 0; mt < 4; mt++) {
      f32x4 sacc[4] = {zero4, zero4, zero4, zero4};
      __builtin_amdgcn_s_setprio(1);
      #pragma unroll
      for (int kc = 0; kc < 2; kc++)
        #pragma unroll
        for (int nt = 0; nt < 4; nt++)
          sacc[nt] = __builtin_amdgcn_mfma_f32_16x16x32_bf16(qf[mt][kc], kf[kc][nt], sacc[nt], 0, 0, 0);
      __builtin_amdgcn_s_setprio(0);
      #pragma unroll
      for (int r = 0; r < 4; r++) {
        const float p0 = __expf(sacc[0][r] * 0.125f);
        const float p1 = __expf(sacc[1][r] * 0.125f);
        const float p2 = __expf(sacc[2][r] * 0.125f);
        const float p3 = __expf(sacc[3][r] * 0.125f);
        lsum[mt][r] += (p0 + p1) + (p2 + p3);
        float2 f01; f01.x = p0; f01.y = p1;
        float2 f23; f23.x = p2; f23.y = p3;
        __hip_bfloat162 b01 = __float22bfloat162_rn(f01);
        __hip_bfloat162 b23 = __float22bfloat162_rn(f23);
        union { __hip_bfloat162 h; unsigned int u; } c0, c1;
        c0.h = b01; c1.h = b23;
        uint2 w; w.x = c0.u; w.y = c1.u;
        const int m = mt * 16 + gr * 4 + r;
        *(uint2*)&Qp[wid][m * 64 + ((cl >> 1) ^ (m & 7)) * 8 + (cl & 1) * 4] = w;
      }
    }

    // BAR1: own ds ops (Vt writes, kf reads, P writes) retired, then join.
    asm volatile("s_waitcnt lgkmcnt(0)" ::: "memory");
    SBAR();
    bar();

    // stage K(tc+1) FIRST, then V-prefetch(tc+1) (vm queue: [K:2][V:8])
    if (tc < 3) {
      #pragma unroll
      for (int i = 0; i < 2; i++) {
        const int r0 = (wid * 2 + i) * 8;
        gl_lds16(kbase + (size_t)((tc + 1) * 64 + r0 + l8) * 3072 + (l7 ^ l8) * 8, &Kt[r0 * 64]);
      }
      #pragma unroll
      for (int i = 0; i < 2; i++) {
        const int u = i * 256 + tid;
        const int t0 = u >> 5, d = (u & 31) * 2;
        #pragma unroll
        for (int k = 0; k < 4; k++)
          vr[i][k] = *(const unsigned int*)(vbase + (size_t)((tc + 1) * 64 + t0 + 16 * k) * 3072 + d);
      }
    }

    // O += P * V (both pi-permuted -> exact)
    #pragma unroll
    for (int kc = 0; kc < 2; kc++) {
      bf16x8 vf[4], pf[4];
      #pragma unroll
      for (int dt = 0; dt < 4; dt++)
        vf[dt] = *(const bf16x8*)&Vt[(dt * 16 + cl) * 64 + ((kc * 4 + gr) ^ (cl & 7)) * 8];
      #pragma unroll
      for (int mt = 0; mt < 4; mt++)
        pf[mt] = *(const bf16x8*)&Qp[wid][(mt * 16 + cl) * 64 + ((kc * 4 + gr) ^ (cl & 7)) * 8];
      __builtin_amdgcn_s_setprio(1);
      #pragma unroll
      for (int mt = 0; mt < 4; mt++)
        #pragma unroll
        for (int dt = 0; dt < 4; dt++)
          o[mt][dt] = __builtin_amdgcn_mfma_f32_16x16x32_bf16(pf[mt], vf[dt], o[mt][dt], 0, 0, 0);
      __builtin_amdgcn_s_setprio(0);
    }

    // BAR2: staged K retired per-wave (V stays in flight), PV reads done.
    if (tc < 3) {
      asm volatile("s_waitcnt vmcnt(8)" ::: "memory");
      SBAR();
      asm volatile("s_waitcnt lgkmcnt(0)" ::: "memory");
      SBAR();
      bar();
    }
  }

  #pragma unroll
  for (int mt = 0; mt < 4; mt++)
    #pragma unroll
    for (int r = 0; r < 4; r++) {
      float l = lsum[mt][r];
      l += __shfl_xor(l, 1);
      l += __shfl_xor(l, 2);
      l += __shfl_xor(l, 4);
      l += __shfl_xor(l, 8);
      const float inv = 1.0f / l;
      const int srow = wid * 64 + mt * 16 + gr * 4 + r;
      #pragma unroll
      for (int dt = 0; dt < 4; dt++)
        attn_out[(size_t)(n * 256 + srow) * 1024 + h * 64 + dt * 16 + cl] =
            f2bf(o[mt][dt][r] * inv);
    }
}

extern "C" void kernel_launch(void* const* d_in, const int* in_sizes, int n_in,
                              void* d_out, int out_size, void* d_ws, size_t ws_size,
                              hipStream_t stream) {
  const float* x      = (const float*)d_in[0];   // (4,32,16,16,1024)
  const float* w_qkv  = (const float*)d_in[1];   // (1024,3072)
  const float* w_proj = (const float*)d_in[2];   // (1024,1024)
  const float* b_proj = (const float*)d_in[3];   // (1024,)
  float* out = (float*)d_out;
  char* ws = (char*)d_ws;

  unsigned short* x_bf    = (unsigned short*)ws;                // 64 MiB (reused as attn out)
  unsigned short* wqkvT   = (unsigned short*)(ws + 67108864);   // [3072][1024]
  unsigned short* wprojT  = (unsigned short*)(ws + 73400320);   // [1024][1024]
  unsigned short* qkvb    = (unsigned short*)(ws + 75497472);   // [32768][3072]
  unsigned short* attn_bf = x_bf;

  k_conv_x<<<32768, 256, 0, stream>>>((const float4*)x, (ushort4_t*)x_bf, 8388608);
  k_transpose_bf16<<<dim3(48, 16), 256, 0, stream>>>(w_qkv, wqkvT, 1024, 3072);
  k_transpose_bf16<<<dim3(16, 16), 256, 0, stream>>>(w_proj, wprojT, 1024, 1024);

  // qkv = x @ w_qkv with fused 2D-RoPE on q,k (M=32768, N=3072, K=1024)
  k_gemm_bt<0, 1><<<dim3(12, 128), 512, 0, stream>>>(x_bf, wqkvT, qkvb, nullptr, nullptr,
                                                     32768, 3072, 1024);
  // flash attention, one block per (n, head)
  k_attn<<<2048, 256, 0, stream>>>(qkvb, attn_bf);

  // out = attn @ w_proj + b_proj (M=32768, N=1024, K=1024)
  k_gemm_bt<1, 0><<<dim3(4, 128), 512, 0, stream>>>(attn_bf, wprojT, nullptr, out, b_proj,
                                                    32768, 1024, 1024);
}

// Round 8
// 571.400 us; speedup vs baseline: 1.2250x; 1.2250x over previous
//
#include <hip/hip_runtime.h>
#include <hip/hip_bf16.h>
#include <stdint.h>

typedef __attribute__((ext_vector_type(8))) short bf16x8;
typedef __attribute__((ext_vector_type(4))) float f32x4;
typedef __attribute__((ext_vector_type(4))) unsigned short ushort4_t;

__device__ __forceinline__ unsigned short f2bf(float f) {
  union { float f; unsigned int i; } x; x.f = f;
  return (unsigned short)((x.i + 0x7fffu + ((x.i >> 16) & 1u)) >> 16);
}

// async global->LDS, 16B per lane; LDS dest is wave-uniform base + lane*16
__device__ __forceinline__ void gl_lds16(const void* g, void* l) {
  __builtin_amdgcn_global_load_lds(
      (const __attribute__((address_space(1))) unsigned int*)(uintptr_t)g,
      (__attribute__((address_space(3))) unsigned int*)(uint32_t)(uintptr_t)l,
      16, 0, 0);
}

// raw barrier (no vmcnt/lgkmcnt drain!) with compiler memory fences
__device__ __forceinline__ void bar() {
  asm volatile("" ::: "memory");
  __builtin_amdgcn_s_barrier();
  asm volatile("" ::: "memory");
}

// inv_freq[j] = 10000^(-j/16), j = 0..15 (d_half=32, 16 freqs)
__constant__ float INVF[16] = {
  1.0f,   0.56234132519f,  0.31622776601f,  0.17782794100f,
  0.1f,   0.056234132519f, 0.031622776601f, 0.017782794100f,
  0.01f,  0.0056234132519f,0.0031622776601f,0.0017782794100f,
  0.001f, 0.00056234132519f,0.00031622776601f,0.00017782794100f
};

// ---- fp32 -> bf16 bulk convert (x) ----
__global__ __launch_bounds__(256) void k_conv_x(const float4* __restrict__ src,
                                                ushort4_t* __restrict__ dst, int n4) {
  int i = blockIdx.x * 256 + threadIdx.x;
  if (i < n4) {
    float4 v = src[i];
    ushort4_t r = { f2bf(v.x), f2bf(v.y), f2bf(v.z), f2bf(v.w) };
    dst[i] = r;
  }
}

// ---- fp32 RxC -> bf16 CxR transpose (weights to B^T layout) ----
__global__ __launch_bounds__(256) void k_transpose_bf16(const float* __restrict__ src,
                                                        unsigned short* __restrict__ dst,
                                                        int R, int C) {
  __shared__ unsigned short tile[64][65];
  const int bj = blockIdx.x, bi = blockIdx.y;
  const int t = threadIdx.x, lr = t >> 6, lc = t & 63;
  #pragma unroll
  for (int i = 0; i < 16; i++) {
    int r = i * 4 + lr;
    tile[r][lc] = f2bf(src[(size_t)(bi * 64 + r) * C + bj * 64 + lc]);
  }
  __syncthreads();
  #pragma unroll
  for (int i = 0; i < 16; i++) {
    int r = i * 4 + lr;
    dst[(size_t)(bj * 64 + r) * R + bi * 64 + lc] = tile[lc][r];
  }
}

// ---- Per-wave software-pipelined GEMM: C[M,N] = A[M,K]*B[N,K]^T ----
// (unchanged from R6 -- best GEMM so far, 214 us / 950 TF.)

#define LDA(dst, base, hm)                                                      \
  do {                                                                          \
    _Pragma("unroll") for (int t_ = 0; t_ < 4; t_++) {                          \
      dst[0][t_] = *(const bf16x8*)&base[(wm * 128 + (hm) * 64 + t_ * 16 + cl) * 64 + cf0]; \
      dst[1][t_] = *(const bf16x8*)&base[(wm * 128 + (hm) * 64 + t_ * 16 + cl) * 64 + cf1]; \
    }                                                                           \
  } while (0)

#define LDB(dst, base, hn)                                                      \
  do {                                                                          \
    _Pragma("unroll") for (int u_ = 0; u_ < 2; u_++) {                          \
      dst[0][u_] = *(const bf16x8*)&base[(wn * 64 + (hn) * 32 + u_ * 16 + cl) * 64 + cf0]; \
      dst[1][u_] = *(const bf16x8*)&base[(wn * 64 + (hn) * 32 + u_ * 16 + cl) * 64 + cf1]; \
    }                                                                           \
  } while (0)

#define MFMA_Q(hm, hn, AFR, BVR)                                                \
  do {                                                                          \
    __builtin_amdgcn_s_setprio(1);                                              \
    _Pragma("unroll") for (int kc_ = 0; kc_ < 2; kc_++)                         \
      _Pragma("unroll") for (int mt_ = 0; mt_ < 4; mt_++)                       \
        _Pragma("unroll") for (int u_ = 0; u_ < 2; u_++)                        \
          acc[(hm) * 4 + mt_][(hn) * 2 + u_] =                                  \
              __builtin_amdgcn_mfma_f32_16x16x32_bf16(                          \
                  AFR[kc_][mt_], BVR[kc_][u_],                                  \
                  acc[(hm) * 4 + mt_][(hn) * 2 + u_], 0, 0, 0);                 \
    __builtin_amdgcn_s_setprio(0);                                              \
  } while (0)

#define STAGE_A(tile_, half_)                                                   \
  do {                                                                          \
    const int so_ = ((tile_) & 1) * 16384;                                      \
    const int ko_ = (tile_) * 64;                                               \
    gl_lds16(aP[(half_) * 2] + ko_,     &As[so_ + ((half_) * 2) * 4096 + ldsW]);     \
    gl_lds16(aP[(half_) * 2 + 1] + ko_, &As[so_ + ((half_) * 2 + 1) * 4096 + ldsW]); \
  } while (0)

#define STAGE_B(tile_, half_)                                                   \
  do {                                                                          \
    const int so_ = ((tile_) & 1) * 16384;                                      \
    const int ko_ = (tile_) * 64;                                               \
    gl_lds16(bP[(half_) * 2] + ko_,     &Bs[so_ + ((half_) * 2) * 4096 + ldsW]);     \
    gl_lds16(bP[(half_) * 2 + 1] + ko_, &Bs[so_ + ((half_) * 2 + 1) * 4096 + ldsW]); \
  } while (0)

#define SBAR() __builtin_amdgcn_sched_barrier(0)

template<int F32OUT, int ROPE>
__global__ __launch_bounds__(512, 2) void k_gemm_bt(
    const unsigned short* __restrict__ A, const unsigned short* __restrict__ B,
    unsigned short* __restrict__ Cb, float* __restrict__ Cf,
    const float* __restrict__ bias, int M, int N, int K) {
  __shared__ __align__(16) unsigned short As[2 * 256 * 64];  // 64 KB
  __shared__ __align__(16) unsigned short Bs[2 * 256 * 64];  // 64 KB
  const int tid = threadIdx.x;
  const int lane = tid & 63, wid = tid >> 6;
  const int cl = lane & 15, gr = lane >> 4;
  const int wm = wid >> 2, wn = wid & 3;     // 2M x 4N wave grid
  const int l8 = lane >> 3, l7 = lane & 7;

  // XCD-aware bijective block swizzle (requires nwg % 8 == 0; holds here)
  const int gx = gridDim.x;
  const int nwg = gx * gridDim.y;
  const int fb = blockIdx.y * gx + blockIdx.x;
  const int q = nwg >> 3;
  const int nid = (fb & 7) * q + (fb >> 3);
  const int bx = nid % gx, by = nid / gx;
  const int mBase = by * 256, nBase = bx * 256;

  const int KT = K >> 6;                 // 64-wide K chunks (16 here)
  const int ldsW = (wid * 8) * 64;       // wave-uniform LDS row-base offset
  const int cf0 = ((0 * 4 + gr) ^ (cl & 7)) * 8;
  const int cf1 = ((1 * 4 + gr) ^ (cl & 7)) * 8;

  // per-thread global source pointers (include row and pre-swizzled chunk)
  const unsigned short* aP[4];
  const unsigned short* bP[4];
  #pragma unroll
  for (int i = 0; i < 4; i++) {
    aP[i] = A + (size_t)(mBase + i * 64 + wid * 8 + l8) * K + (l7 ^ l8) * 8;
    bP[i] = B + (size_t)(nBase + i * 64 + wid * 8 + l8) * K + (l7 ^ l8) * 8;
  }

  const f32x4 zero4 = {0.f, 0.f, 0.f, 0.f};
  f32x4 acc[8][4];
  #pragma unroll
  for (int a = 0; a < 8; a++)
    #pragma unroll
    for (int b = 0; b < 4; b++) acc[a][b] = zero4;

  // prologue: stage tile 0 into slot 0, wait, publish
  STAGE_A(0, 0); STAGE_A(0, 1); STAGE_B(0, 0); STAGE_B(0, 1);
  asm volatile("s_waitcnt vmcnt(0)" ::: "memory");
  bar();

  bf16x8 af0[2][4], af1[2][4], bva[2][2], bvb[2][2];

  for (int c = 0; c < KT; ++c) {
    const int s = c & 1;
    const unsigned short* as_ = As + s * 16384;
    const unsigned short* bs_ = Bs + s * 16384;

    // stage tile c+1 into the other slot (async, vm-counted)
    if (c + 1 < KT) {
      STAGE_A(c + 1, 0); STAGE_A(c + 1, 1);
      STAGE_B(c + 1, 0); STAGE_B(c + 1, 1);
    }

    // ds-issue in counted order: [af0:8][bva:4] [bvb:4] [af1:8]
    LDA(af0, as_, 0);
    LDB(bva, bs_, 0);
    SBAR();
    LDB(bvb, bs_, 1);
    SBAR();
    LDA(af1, as_, 1);
    SBAR();

    asm volatile("s_waitcnt lgkmcnt(12)" ::: "memory");  // af0+bva landed
    SBAR();
    MFMA_Q(0, 0, af0, bva);
    asm volatile("s_waitcnt lgkmcnt(8)" ::: "memory");   // bvb landed
    SBAR();
    MFMA_Q(0, 1, af0, bvb);
    asm volatile("s_waitcnt lgkmcnt(0)" ::: "memory");   // af1 landed
    SBAR();
    MFMA_Q(1, 1, af1, bvb);
    MFMA_Q(1, 0, af1, bva);

    // tile end: publish staged tile c+1 (issued a full tile earlier)
    if (c + 1 < KT) {
      asm volatile("s_waitcnt vmcnt(0)" ::: "memory");
      bar();
    }
  }

  if (ROPE && nBase < 2048) {  // q or k region of qkv output (wave-uniform)
    const float f2 = INVF[cl];
    #pragma unroll
    for (int amt = 0; amt < 8; amt++)
      #pragma unroll
      for (int r = 0; r < 4; r++) {
        const int sp = (mBase + wm * 128 + amt * 16 + gr * 4 + r) & 255;
        float sh, ch, sw, cw;
        __sincosf((float)(sp >> 4) * f2, &sh, &ch);
        __sincosf((float)(sp & 15) * f2, &sw, &cw);
        const float a = acc[amt][0][r], b = acc[amt][1][r];
        const float cc = acc[amt][2][r], d = acc[amt][3][r];
        acc[amt][0][r] = a * ch - b * sh;
        acc[amt][1][r] = b * ch + a * sh;
        acc[amt][2][r] = cc * cw - d * sw;
        acc[amt][3][r] = d * cw + cc * sw;
      }
  }

  // C/D layout (m89-verified): col = lane&15, row = (lane>>4)*4 + reg
  #pragma unroll
  for (int amt = 0; amt < 8; amt++)
    #pragma unroll
    for (int nt = 0; nt < 4; nt++)
      #pragma unroll
      for (int r = 0; r < 4; r++) {
        const int row = mBase + wm * 128 + amt * 16 + gr * 4 + r;
        const int col = nBase + wn * 64 + nt * 16 + cl;
        const float v = acc[amt][nt][r];
        if (F32OUT) Cf[(size_t)row * N + col] = v + bias[col];
        else        Cb[(size_t)row * N + col] = f2bf(v);
      }
}

// ---- flash attention (RoPE pre-applied): one block per (n, head); 4 waves x 64 q
//
// R8 structure: K is only 32 KB/head -> stage ALL of K in the prologue.
// The tc-loop then has ZERO gl_lds and ZERO vmcnt coupling (R7's regression
// was the in-loop vmcnt(8) pinning K-stage HBM latency onto the critical
// path). Vt is double-buffered (2x8 KB) so the only cross-wave hazard
// alternates buffers -> ONE raw barrier per tc (was 2 x __syncthreads with
// full vmcnt(0)+lgkmcnt(0) drains).
// Hazard audit:
//  - Vt[b] write-visible: writes at tc start, reads (PV) after bar(tc). ok.
//  - Vt[b] overwrite (tc+2) is 2 barriers after its last PV read; each wave's
//    PV reads are consumed by its MFMAs before it reaches bar(tc+1). ok.
//  - P lives in wave-private Qp[wid]: in-wave DS program order + compiler
//    lgkmcnt on MFMA operands. no cross-wave visibility needed. ok.
//  - Kt read-only after prologue __syncthreads. ok.
//  - V(tc+1) global->reg loads issued before bar(tc), consumed at next
//    Vt write (compiler-inserted vmcnt) -- stay in flight across barrier. ok.
// kf hoisted (8 b128/tc instead of 32); setprio around MFMA clusters (m191).
// LDS 32(Qp)+32(K)+16(Vt) = 80 KB -> 2 blocks/CU.
__global__ __launch_bounds__(256, 2) void k_attn(const unsigned short* __restrict__ qkv,
                                                 unsigned short* __restrict__ attn_out) {
  __shared__ __align__(16) unsigned short Qp[4][64 * 64];   // per-wave Q, then P
  __shared__ __align__(16) unsigned short Kt[4][64 * 64];   // ALL of K, resident
  __shared__ __align__(16) unsigned short Vt[2][64 * 64];   // V^T dbuf, pi-permuted
  const int blk = blockIdx.x;
  const int n = blk >> 4, h = blk & 15;
  const int tid = threadIdx.x;
  const int lane = tid & 63, wid = tid >> 6;
  const int cl = lane & 15, gr = lane >> 4;
  const int l8 = lane >> 3, l7 = lane & 7;
  const unsigned short* qbase = qkv + (size_t)n * 256 * 3072 + h * 64;
  const unsigned short* kbase = qbase + 1024;
  const unsigned short* vbase = qbase + 2048;

  // stage Q (own wave's 64 rows) + ALL of K (4 chunks, split across waves)
  #pragma unroll
  for (int i = 0; i < 8; i++)
    gl_lds16(qbase + (size_t)(wid * 64 + i * 8 + l8) * 3072 + (l7 ^ l8) * 8,
             &Qp[wid][i * 8 * 64]);
  #pragma unroll
  for (int c = 0; c < 4; c++)
    #pragma unroll
    for (int i = 0; i < 2; i++) {
      const int r0 = (wid * 2 + i) * 8;
      gl_lds16(kbase + (size_t)(c * 64 + r0 + l8) * 3072 + (l7 ^ l8) * 8,
               &Kt[c][r0 * 64]);
    }

  // V(0) register prefetch: unit u = i*256+tid: t0 = u>>5, d = (u&31)*2
  unsigned int vr[2][4];
  #pragma unroll
  for (int i = 0; i < 2; i++) {
    const int u = i * 256 + tid;
    const int t0 = u >> 5, d = (u & 31) * 2;
    #pragma unroll
    for (int k = 0; k < 4; k++)
      vr[i][k] = *(const unsigned int*)(vbase + (size_t)(t0 + 16 * k) * 3072 + d);
  }
  __syncthreads();   // prologue full drain (once)

  bf16x8 qf[4][2];
  #pragma unroll
  for (int mt = 0; mt < 4; mt++)
    #pragma unroll
    for (int kc = 0; kc < 2; kc++)
      qf[mt][kc] = *(const bf16x8*)&Qp[wid][(mt * 16 + cl) * 64 + ((kc * 4 + gr) ^ (cl & 7)) * 8];

  const f32x4 zero4 = {0.f, 0.f, 0.f, 0.f};
  f32x4 o[4][4];
  float lsum[4][4];
  #pragma unroll
  for (int a = 0; a < 4; a++)
    #pragma unroll
    for (int b = 0; b < 4; b++) { o[a][b] = zero4; lsum[a][b] = 0.f; }

  for (int tc = 0; tc < 4; tc++) {
    const int vb = tc & 1;
    // write V(tc) regs -> Vt[vb], permuted + swizzled
    #pragma unroll
    for (int i = 0; i < 2; i++) {
      const int u = i * 256 + tid;
      const int t0 = u >> 5, d = (u & 31) * 2;
      const unsigned int r0 = vr[i][0], r1 = vr[i][1], r2 = vr[i][2], r3 = vr[i][3];
      uint2 lo, hi;
      lo.x = (r0 & 0xffffu) | (r1 << 16);
      lo.y = (r2 & 0xffffu) | (r3 << 16);
      hi.x = (r0 >> 16) | (r1 & 0xffff0000u);
      hi.y = (r2 >> 16) | (r3 & 0xffff0000u);
      *(uint2*)&Vt[vb][d * 64 + ((t0 >> 1) ^ (d & 7)) * 8 + (t0 & 1) * 4] = lo;
      const int d1 = d + 1;
      *(uint2*)&Vt[vb][d1 * 64 + ((t0 >> 1) ^ (d1 & 7)) * 8 + (t0 & 1) * 4] = hi;
    }
    // prefetch V(tc+1) into regs (in flight across the barrier)
    if (tc < 3) {
      #pragma unroll
      for (int i = 0; i < 2; i++) {
        const int u = i * 256 + tid;
        const int t0 = u >> 5, d = (u & 31) * 2;
        #pragma unroll
        for (int k = 0; k < 4; k++)
          vr[i][k] = *(const unsigned int*)(vbase + (size_t)((tc + 1) * 64 + t0 + 16 * k) * 3072 + d);
      }
    }

    // hoisted K fragments for this K-tile from resident Kt (8 b128)
    bf16x8 kf[2][4];
    #pragma unroll
    for (int kc = 0; kc < 2; kc++)
      #pragma unroll
      for (int nt = 0; nt < 4; nt++)
        kf[kc][nt] = *(const bf16x8*)&Kt[tc][(nt * 16 + cl) * 64 + ((kc * 4 + gr) ^ (cl & 7)) * 8];

    // QK + exp + P write, one mt at a time
    #pragma unroll
    for (int mt = 0; mt < 4; mt++) {
      f32x4 sacc[4] = {zero4, zero4, zero4, zero4};
      __builtin_amdgcn_s_setprio(1);
      #pragma unroll
      for (int kc = 0; kc < 2; kc++)
        #pragma unroll
        for (int nt = 0; nt < 4; nt++)
          sacc[nt] = __builtin_amdgcn_mfma_f32_16x16x32_bf16(qf[mt][kc], kf[kc][nt], sacc[nt], 0, 0, 0);
      __builtin_amdgcn_s_setprio(0);
      #pragma unroll
      for (int r = 0; r < 4; r++) {
        const float p0 = __expf(sacc[0][r] * 0.125f);
        const float p1 = __expf(sacc[1][r] * 0.125f);
        const float p2 = __expf(sacc[2][r] * 0.125f);
        const float p3 = __expf(sacc[3][r] * 0.125f);
        lsum[mt][r] += (p0 + p1) + (p2 + p3);
        float2 f01; f01.x = p0; f01.y = p1;
        float2 f23; f23.x = p2; f23.y = p3;
        __hip_bfloat162 b01 = __float22bfloat162_rn(f01);
        __hip_bfloat162 b23 = __float22bfloat162_rn(f23);
        union { __hip_bfloat162 h; unsigned int u; } c0, c1;
        c0.h = b01; c1.h = b23;
        uint2 w; w.x = c0.u; w.y = c1.u;
        const int m = mt * 16 + gr * 4 + r;
        *(uint2*)&Qp[wid][m * 64 + ((cl >> 1) ^ (m & 7)) * 8 + (cl & 1) * 4] = w;
      }
    }

    // the ONE barrier: own ds ops retired, then Vt[vb]+P visible everywhere
    asm volatile("s_waitcnt lgkmcnt(0)" ::: "memory");
    SBAR();
    bar();

    // O += P * V (both pi-permuted -> exact)
    #pragma unroll
    for (int kc = 0; kc < 2; kc++) {
      bf16x8 vf[4], pf[4];
      #pragma unroll
      for (int dt = 0; dt < 4; dt++)
        vf[dt] = *(const bf16x8*)&Vt[vb][(dt * 16 + cl) * 64 + ((kc * 4 + gr) ^ (cl & 7)) * 8];
      #pragma unroll
      for (int mt = 0; mt < 4; mt++)
        pf[mt] = *(const bf16x8*)&Qp[wid][(mt * 16 + cl) * 64 + ((kc * 4 + gr) ^ (cl & 7)) * 8];
      __builtin_amdgcn_s_setprio(1);
      #pragma unroll
      for (int mt = 0; mt < 4; mt++)
        #pragma unroll
        for (int dt = 0; dt < 4; dt++)
          o[mt][dt] = __builtin_amdgcn_mfma_f32_16x16x32_bf16(pf[mt], vf[dt], o[mt][dt], 0, 0, 0);
      __builtin_amdgcn_s_setprio(0);
    }
  }

  #pragma unroll
  for (int mt = 0; mt < 4; mt++)
    #pragma unroll
    for (int r = 0; r < 4; r++) {
      float l = lsum[mt][r];
      l += __shfl_xor(l, 1);
      l += __shfl_xor(l, 2);
      l += __shfl_xor(l, 4);
      l += __shfl_xor(l, 8);
      const float inv = 1.0f / l;
      const int srow = wid * 64 + mt * 16 + gr * 4 + r;
      #pragma unroll
      for (int dt = 0; dt < 4; dt++)
        attn_out[(size_t)(n * 256 + srow) * 1024 + h * 64 + dt * 16 + cl] =
            f2bf(o[mt][dt][r] * inv);
    }
}

extern "C" void kernel_launch(void* const* d_in, const int* in_sizes, int n_in,
                              void* d_out, int out_size, void* d_ws, size_t ws_size,
                              hipStream_t stream) {
  const float* x      = (const float*)d_in[0];   // (4,32,16,16,1024)
  const float* w_qkv  = (const float*)d_in[1];   // (1024,3072)
  const float* w_proj = (const float*)d_in[2];   // (1024,1024)
  const float* b_proj = (const float*)d_in[3];   // (1024,)
  float* out = (float*)d_out;
  char* ws = (char*)d_ws;

  unsigned short* x_bf    = (unsigned short*)ws;                // 64 MiB (reused as attn out)
  unsigned short* wqkvT   = (unsigned short*)(ws + 67108864);   // [3072][1024]
  unsigned short* wprojT  = (unsigned short*)(ws + 73400320);   // [1024][1024]
  unsigned short* qkvb    = (unsigned short*)(ws + 75497472);   // [32768][3072]
  unsigned short* attn_bf = x_bf;

  k_conv_x<<<32768, 256, 0, stream>>>((const float4*)x, (ushort4_t*)x_bf, 8388608);
  k_transpose_bf16<<<dim3(48, 16), 256, 0, stream>>>(w_qkv, wqkvT, 1024, 3072);
  k_transpose_bf16<<<dim3(16, 16), 256, 0, stream>>>(w_proj, wprojT, 1024, 1024);

  // qkv = x @ w_qkv with fused 2D-RoPE on q,k (M=32768, N=3072, K=1024)
  k_gemm_bt<0, 1><<<dim3(12, 128), 512, 0, stream>>>(x_bf, wqkvT, qkvb, nullptr, nullptr,
                                                     32768, 3072, 1024);
  // flash attention, one block per (n, head)
  k_attn<<<2048, 256, 0, stream>>>(qkvb, attn_bf);

  // out = attn @ w_proj + b_proj (M=32768, N=1024, K=1024)
  k_gemm_bt<1, 0><<<dim3(4, 128), 512, 0, stream>>>(attn_bf, wprojT, nullptr, out, b_proj,
                                                    32768, 1024, 1024);
}